// Round 19
// baseline (206.350 us; speedup 1.0000x reference)
//
#include <hip/hip_runtime.h>
#include <math.h>

// Problem dims (fixed)
#define NN 4096     // nodes
#define DD 400      // input feature dim
#define HH 256      // GCN hidden
#define FF 128      // GAT out dim
#define PH 128      // predictor hidden
#define YY 5        // classes

typedef float f32x4v __attribute__((ext_vector_type(4)));
typedef short bf16x8 __attribute__((ext_vector_type(8)));
typedef short bf16x4 __attribute__((ext_vector_type(4)));

__device__ __forceinline__ float lrelu(float v) { return v >= 0.f ? v : 0.25f * v; }
// fp32 -> bf16 round-to-nearest-even
__device__ __forceinline__ short f2b(float f) {
    unsigned u = __float_as_uint(f);
    unsigned r = (u + 0x7fffu + ((u >> 16) & 1u)) >> 16;
    return (short)r;
}
__device__ __forceinline__ float b2f(short s) {
    return __uint_as_float((unsigned)(unsigned short)s << 16);
}

// Raw LDS-visibility barrier (no vmcnt drain).
__device__ __forceinline__ void bar_stage() {
    asm volatile("s_waitcnt lgkmcnt(0)" ::: "memory");
    __builtin_amdgcn_sched_barrier(0);
    __builtin_amdgcn_s_barrier();
    __builtin_amdgcn_sched_barrier(0);
}
__device__ __forceinline__ void bar_read() {
    __builtin_amdgcn_sched_barrier(0);
    __builtin_amdgcn_s_barrier();
    __builtin_amdgcn_sched_barrier(0);
}

// async global->LDS DMA, 16B per lane (LDS dest = wave-uniform base + lane*16)
__device__ __forceinline__ void gload_lds16(const float* g, float* l) {
    __builtin_amdgcn_global_load_lds(
        (const __attribute__((address_space(1))) void*)g,
        (__attribute__((address_space(3))) void*)l, 16, 0, 0);
}

// ---------------------------------------------------------------------------
// Weight prep: in [R,C] fp32 -> out [C,RP] bf16 (transpose, zero-pad rows>=R)
// ---------------------------------------------------------------------------
__global__ __launch_bounds__(256) void transpose_f2b_pad(
    const float* __restrict__ in0, const float* __restrict__ in1,
    short* __restrict__ out0, short* __restrict__ out1, int R, int C, int RP)
{
    const float* in = blockIdx.z ? in1 : in0;
    short* out      = blockIdx.z ? out1 : out0;
    __shared__ float T[32][33];
    const int r0 = blockIdx.y * 32, c0 = blockIdx.x * 32;
    const int t = threadIdx.x, r = t >> 5, c = t & 31;
    #pragma unroll
    for (int p = 0; p < 4; ++p) {
        int rr = r0 + r + p * 8;
        T[r + p * 8][c] = (rr < R) ? in[(size_t)rr * C + c0 + c] : 0.f;
    }
    __syncthreads();
    #pragma unroll
    for (int p = 0; p < 4; ++p)
        out[(size_t)(c0 + r + p * 8) * RP + r0 + c] = f2b(T[c][r + p * 8]);
}

// ---------------------------------------------------------------------------
// Generic bf16 MFMA GEMM (steps 1,3,5). WHF: fragment-tiled output
// CF[m/32][n=N][m&31] (tile = N*32 shorts). WC: row-major fp32 C.
// ---------------------------------------------------------------------------
struct PrefMM {
    float4 a0, a1, a2, a3;    // A fp32 path
    bf16x8 ab0, ab1;          // A bf16 path
    bf16x8 b0, b1;            // B
};

template<bool ABF16, bool WC, bool WHF, int KSTEPS>
__global__ __launch_bounds__(256) void gemm_mfma_gen(
    const void* __restrict__ A0, const void* __restrict__ A1,
    const short* __restrict__ BT0, const short* __restrict__ BT1,
    float* __restrict__ C0, float* __restrict__ C1,
    short* __restrict__ CT0, short* __restrict__ CT1,
    int lda, int ldb, int N, int kvalid)
{
    const void* A   = blockIdx.z ? A1 : A0;
    const short* BT = blockIdx.z ? BT1 : BT0;
    float* C        = blockIdx.z ? C1 : C0;
    short* CT       = blockIdx.z ? CT1 : CT0;

    __shared__ short As[64 * 88];
    __shared__ short Bs[64 * 88];

    const int tid = threadIdx.x;
    const int m0 = blockIdx.y * 64, n0 = blockIdx.x * 64;
    const int l = tid & 63, w = tid >> 6;
    const int wr = w >> 1, wc = w & 1;
    const int fr = l & 15, fq = l >> 4;
    const int sr = tid >> 2, sk = (tid & 3) * 16;

    const float* Apf = (const float*)A + (size_t)(m0 + sr) * lda + sk;
    const short* Apb = (const short*)A + (size_t)(m0 + sr) * lda + sk;
    const short* Bp  = BT + (size_t)(n0 + sr) * ldb + sk;

    short* As_w = As + sr * 88 + sk;
    short* Bs_w = Bs + sr * 88 + sk;
    const short* Af = As + (wr * 32 + fr) * 88 + fq * 8;
    const short* Bf = Bs + (wc * 32 + fr) * 88 + fq * 8;

    f32x4v acc00 = {0.f,0.f,0.f,0.f}, acc01 = {0.f,0.f,0.f,0.f};
    f32x4v acc10 = {0.f,0.f,0.f,0.f}, acc11 = {0.f,0.f,0.f,0.f};

    PrefMM P[2];

    auto loadr = [&](PrefMM& Pr, int t) {
        const int kk = t * 64;
        const bool valid = (kk + sk) < kvalid;
        if (ABF16) {
            if (valid) {
                Pr.ab0 = *(const bf16x8*)(Apb + kk);
                Pr.ab1 = *(const bf16x8*)(Apb + kk + 8);
            } else {
                Pr.ab0 = (bf16x8)0; Pr.ab1 = (bf16x8)0;
            }
        } else {
            if (valid) {
                Pr.a0 = *(const float4*)(Apf + kk);
                Pr.a1 = *(const float4*)(Apf + kk + 4);
                Pr.a2 = *(const float4*)(Apf + kk + 8);
                Pr.a3 = *(const float4*)(Apf + kk + 12);
            } else {
                Pr.a0 = Pr.a1 = Pr.a2 = Pr.a3 = make_float4(0.f, 0.f, 0.f, 0.f);
            }
        }
        Pr.b0 = *(const bf16x8*)(Bp + kk);
        Pr.b1 = *(const bf16x8*)(Bp + kk + 8);
    };

    auto stage = [&](PrefMM& Pr) {
        if (ABF16) {
            *(bf16x8*)(As_w)     = Pr.ab0;
            *(bf16x8*)(As_w + 8) = Pr.ab1;
        } else {
            bf16x8 v0, v1;
            v0[0] = f2b(Pr.a0.x); v0[1] = f2b(Pr.a0.y); v0[2] = f2b(Pr.a0.z); v0[3] = f2b(Pr.a0.w);
            v0[4] = f2b(Pr.a1.x); v0[5] = f2b(Pr.a1.y); v0[6] = f2b(Pr.a1.z); v0[7] = f2b(Pr.a1.w);
            v1[0] = f2b(Pr.a2.x); v1[1] = f2b(Pr.a2.y); v1[2] = f2b(Pr.a2.z); v1[3] = f2b(Pr.a2.w);
            v1[4] = f2b(Pr.a3.x); v1[5] = f2b(Pr.a3.y); v1[6] = f2b(Pr.a3.z); v1[7] = f2b(Pr.a3.w);
            *(bf16x8*)(As_w)     = v0;
            *(bf16x8*)(As_w + 8) = v1;
        }
        *(bf16x8*)(Bs_w)     = Pr.b0;
        *(bf16x8*)(Bs_w + 8) = Pr.b1;
    };

    auto mfma16 = [&]() {
        bf16x8 A00 = *(const bf16x8*)(Af);
        bf16x8 A10 = *(const bf16x8*)(Af + 16 * 88);
        bf16x8 A01 = *(const bf16x8*)(Af + 32);
        bf16x8 A11 = *(const bf16x8*)(Af + 16 * 88 + 32);
        bf16x8 B00 = *(const bf16x8*)(Bf);
        bf16x8 B10 = *(const bf16x8*)(Bf + 16 * 88);
        bf16x8 B01 = *(const bf16x8*)(Bf + 32);
        bf16x8 B11 = *(const bf16x8*)(Bf + 16 * 88 + 32);
        acc00 = __builtin_amdgcn_mfma_f32_16x16x32_bf16(A00, B00, acc00, 0, 0, 0);
        acc01 = __builtin_amdgcn_mfma_f32_16x16x32_bf16(A00, B10, acc01, 0, 0, 0);
        acc10 = __builtin_amdgcn_mfma_f32_16x16x32_bf16(A10, B00, acc10, 0, 0, 0);
        acc11 = __builtin_amdgcn_mfma_f32_16x16x32_bf16(A10, B10, acc11, 0, 0, 0);
        acc00 = __builtin_amdgcn_mfma_f32_16x16x32_bf16(A01, B01, acc00, 0, 0, 0);
        acc01 = __builtin_amdgcn_mfma_f32_16x16x32_bf16(A01, B11, acc01, 0, 0, 0);
        acc10 = __builtin_amdgcn_mfma_f32_16x16x32_bf16(A11, B01, acc10, 0, 0, 0);
        acc11 = __builtin_amdgcn_mfma_f32_16x16x32_bf16(A11, B11, acc11, 0, 0, 0);
    };

    loadr(P[0], 0);
    #pragma unroll
    for (int t = 0; t < KSTEPS; ++t) {
        if (t + 1 < KSTEPS) loadr(P[(t + 1) & 1], t + 1);
        stage(P[t & 1]);
        bar_stage();
        mfma16();
        bar_read();
    }

    const int crow = m0 + wr * 32 + fq * 4;
    const int col0 = n0 + wc * 32 + fr;
    if (WHF) {
        const int jt = (m0 >> 5) + wr;
        short* hf = CT + (size_t)jt * (N * 32) + fq * 4;
        bf16x4 u;
        u[0]=f2b(acc00[0]); u[1]=f2b(acc00[1]); u[2]=f2b(acc00[2]); u[3]=f2b(acc00[3]);
        *(bf16x4*)(hf + col0 * 32) = u;
        u[0]=f2b(acc01[0]); u[1]=f2b(acc01[1]); u[2]=f2b(acc01[2]); u[3]=f2b(acc01[3]);
        *(bf16x4*)(hf + (col0 + 16) * 32) = u;
        u[0]=f2b(acc10[0]); u[1]=f2b(acc10[1]); u[2]=f2b(acc10[2]); u[3]=f2b(acc10[3]);
        *(bf16x4*)(hf + col0 * 32 + 16) = u;
        u[0]=f2b(acc11[0]); u[1]=f2b(acc11[1]); u[2]=f2b(acc11[2]); u[3]=f2b(acc11[3]);
        *(bf16x4*)(hf + (col0 + 16) * 32 + 16) = u;
    }
    if (WC) {
        #pragma unroll
        for (int q = 0; q < 4; ++q) {
            C[(size_t)(crow + q) * N + col0]           = acc00[q];
            C[(size_t)(crow + q) * N + col0 + 16]      = acc01[q];
            C[(size_t)(crow + 16 + q) * N + col0]      = acc10[q];
            C[(size_t)(crow + 16 + q) * N + col0 + 16] = acc11[q];
        }
    }
}

// ---------------------------------------------------------------------------
// adj GEMM (steps 2,4): A staged via global_load_lds DMA (fp32, source-side
// XOR swizzle, double-buffered 2x8KB LDS); counted vmcnt(9) - never drained.
// fp32->bf16 at fragment-read via v_perm truncation. B direct from frag-tiled
// STf (unchanged). Split-K=2. grid (128, 2 sp, 2 mod) = 512 blocks.
// ---------------------------------------------------------------------------
struct PBf  { bf16x8 b00, b01, b10, b11; };

template<bool WMASK>
__global__ __launch_bounds__(512) void gemm_mfma_adj(
    const float* __restrict__ A0p, const float* __restrict__ A1p,
    const short* __restrict__ BF0, const short* __restrict__ BF1,
    short* __restrict__ pacc,
    unsigned char* __restrict__ MK0, unsigned char* __restrict__ MK1)
{
    const int sp = blockIdx.y, z = blockIdx.z;
    const float* A    = z ? A1p : A0p;
    const short* BF   = z ? BF1 : BF0;
    unsigned char* MK = z ? MK1 : MK0;
    const int kbase = sp * 2048;

    __shared__ float As[2][32 * 64];   // 2 x 8KB, linear [row][k], src-swizzled

    const int tid = threadIdx.x;
    const int m0 = blockIdx.x * 32;
    const int w = tid >> 6, l = tid & 63;
    const int fr = l & 15, fq = l >> 4;

    // DMA geometry: wave w covers rows w*4..w*4+3; lane -> row w*4+(l>>4), slot l&15
    const int drow = w * 4 + (l >> 4);
    const int dsrcf = ((l & 15) * 4) ^ ((drow & 7) << 2);  // swizzled float offset in row
    const float* dg = A + (size_t)(m0 + drow) * 4096 + kbase + dsrcf;
    float* dl0 = &As[0][w * 256];   // wave-uniform LDS base (HW adds lane*16B)
    float* dl1 = &As[1][w * 256];

    // B fragment base (frag-tiled STf[kt][256][32])
    const short* Bp = BF + (size_t)(sp * 64) * 8192 + (w * 32 + fr) * 32 + fq * 8;

    // fragment read offsets (floats), read-side XOR matches source swizzle
    const int x = fr & 7;
    const int s00a = fr * 64 + (((2 * fq)     ^ x) << 2);
    const int s00b = fr * 64 + (((2 * fq + 1) ^ x) << 2);
    const int s01a = fr * 64 + (((2 * fq + 8) ^ x) << 2);
    const int s01b = fr * 64 + (((2 * fq + 9) ^ x) << 2);
    const int R16 = 16 * 64;

    unsigned char* mrow0 = MK + (size_t)(m0 + fr) * 512 + sp * 256;
    unsigned char* mrow1 = MK + (size_t)(m0 + 16 + fr) * 512 + sp * 256;

    f32x4v acc00 = {0.f,0.f,0.f,0.f}, acc01 = {0.f,0.f,0.f,0.f};
    f32x4v acc10 = {0.f,0.f,0.f,0.f}, acc11 = {0.f,0.f,0.f,0.f};

    PBf B0r, B1r;

    auto loadB = [&](PBf& P, int it) {
        const short* tb = Bp + (size_t)(it * 2) * 8192;
        P.b00 = *(const bf16x8*)(tb);
        P.b01 = *(const bf16x8*)(tb + 512);          // cols +16
        P.b10 = *(const bf16x8*)(tb + 8192);         // kt+1
        P.b11 = *(const bf16x8*)(tb + 8192 + 512);
    };
    auto dmaA = [&](float* buf, int it) {
        gload_lds16(dg + it * 64, buf);
    };
    auto cvt8 = [](uint4 a, uint4 b) {               // truncating fp32->bf16 pack
        union { unsigned u[4]; bf16x8 v; } r;
        r.u[0] = __builtin_amdgcn_perm(a.y, a.x, 0x07060302u);
        r.u[1] = __builtin_amdgcn_perm(a.w, a.z, 0x07060302u);
        r.u[2] = __builtin_amdgcn_perm(b.y, b.x, 0x07060302u);
        r.u[3] = __builtin_amdgcn_perm(b.w, b.z, 0x07060302u);
        return r.v;
    };
    auto msk8 = [](uint4 a, uint4 b) -> unsigned {   // (int)u>0 == f>0.0f
        unsigned m = 0;
        m |= ((int)a.x > 0) ? 1u : 0u;   m |= ((int)a.y > 0) ? 2u : 0u;
        m |= ((int)a.z > 0) ? 4u : 0u;   m |= ((int)a.w > 0) ? 8u : 0u;
        m |= ((int)b.x > 0) ? 16u : 0u;  m |= ((int)b.y > 0) ? 32u : 0u;
        m |= ((int)b.z > 0) ? 64u : 0u;  m |= ((int)b.w > 0) ? 128u : 0u;
        return m;
    };

    auto consume = [&](const float* base, PBf& B, int it) {
        uint4 a00a = *(const uint4*)(base + s00a);
        uint4 a00b = *(const uint4*)(base + s00b);
        uint4 a01a = *(const uint4*)(base + s01a);
        uint4 a01b = *(const uint4*)(base + s01b);
        uint4 a10a = *(const uint4*)(base + R16 + s00a);
        uint4 a10b = *(const uint4*)(base + R16 + s00b);
        uint4 a11a = *(const uint4*)(base + R16 + s01a);
        uint4 a11b = *(const uint4*)(base + R16 + s01b);
        if (WMASK && w == 0) {
            mrow0[it * 8 + fq]     = (unsigned char)msk8(a00a, a00b);
            mrow0[it * 8 + 4 + fq] = (unsigned char)msk8(a01a, a01b);
            mrow1[it * 8 + fq]     = (unsigned char)msk8(a10a, a10b);
            mrow1[it * 8 + 4 + fq] = (unsigned char)msk8(a11a, a11b);
        }
        bf16x8 A00 = cvt8(a00a, a00b);
        bf16x8 A01 = cvt8(a01a, a01b);
        bf16x8 A10 = cvt8(a10a, a10b);
        bf16x8 A11 = cvt8(a11a, a11b);
        acc00 = __builtin_amdgcn_mfma_f32_16x16x32_bf16(A00, B.b00, acc00, 0, 0, 0);
        acc01 = __builtin_amdgcn_mfma_f32_16x16x32_bf16(A00, B.b01, acc01, 0, 0, 0);
        acc10 = __builtin_amdgcn_mfma_f32_16x16x32_bf16(A10, B.b00, acc10, 0, 0, 0);
        acc11 = __builtin_amdgcn_mfma_f32_16x16x32_bf16(A10, B.b01, acc11, 0, 0, 0);
        acc00 = __builtin_amdgcn_mfma_f32_16x16x32_bf16(A01, B.b10, acc00, 0, 0, 0);
        acc01 = __builtin_amdgcn_mfma_f32_16x16x32_bf16(A01, B.b11, acc01, 0, 0, 0);
        acc10 = __builtin_amdgcn_mfma_f32_16x16x32_bf16(A11, B.b10, acc10, 0, 0, 0);
        acc11 = __builtin_amdgcn_mfma_f32_16x16x32_bf16(A11, B.b11, acc11, 0, 0, 0);
    };

    // prologue: 2 tiles in flight; wait only the first (vmcnt(9))
    dmaA(dl0, 0);
    loadB(B0r, 0);
    dmaA(dl1, 1);
    loadB(B1r, 1);
    asm volatile("s_waitcnt vmcnt(9)" ::: "memory");
    __builtin_amdgcn_sched_barrier(0);
    __builtin_amdgcn_s_barrier();
    __builtin_amdgcn_sched_barrier(0);

    for (int it = 0; it < 32; it += 2) {
        consume(As[0], B0r, it);
        bar_read();                               // all waves done with As[0]
        if (it + 2 < 32) {
            dmaA(dl0, it + 2);
            loadB(B0r, it + 2);
            asm volatile("s_waitcnt vmcnt(9)" ::: "memory");
        } else {
            asm volatile("s_waitcnt vmcnt(4)" ::: "memory");
        }
        __builtin_amdgcn_sched_barrier(0);
        __builtin_amdgcn_s_barrier();             // tile it+1 landed everywhere
        __builtin_amdgcn_sched_barrier(0);

        consume(As[1], B1r, it + 1);
        if (it + 2 < 32) {
            bar_read();                           // all waves done with As[1]
            dmaA(dl1, it + 3);
            loadB(B1r, it + 3);
            asm volatile("s_waitcnt vmcnt(9)" ::: "memory");
            __builtin_amdgcn_sched_barrier(0);
            __builtin_amdgcn_s_barrier();         // tile it+2 landed everywhere
            __builtin_amdgcn_sched_barrier(0);
        }
    }

    const int ccol = w * 32 + fr;
    #pragma unroll
    for (int q = 0; q < 4; ++q) {
        short* P0 = pacc + ((size_t)(z * 2 + sp) * NN + m0 + fq * 4 + q) * HH;
        short* P1 = P0 + 16 * HH;
        P0[ccol]      = f2b(acc00[q]);
        P0[ccol + 16] = f2b(acc01[q]);
        P1[ccol]      = f2b(acc10[q]);
        P1[ccol + 16] = f2b(acc11[q]);
    }
}

// ---------------------------------------------------------------------------
// Combine split-K partials: X = bf16(lrelu(p0 + p1 + bias)). 8 cols/thread.
// ---------------------------------------------------------------------------
__global__ __launch_bounds__(256) void adj_combine(
    const short* __restrict__ pacc,
    const float* __restrict__ bias0, const float* __restrict__ bias1,
    short* __restrict__ X0, short* __restrict__ X1)
{
    const int idx = blockIdx.x * 256 + threadIdx.x;   // 0 .. 2*4096*32-1
    const int z = idx >> 17, rem = idx & 131071;
    const int row = rem >> 5, c8 = (rem & 31) * 8;
    const short* p0 = pacc + ((size_t)(z * 2 + 0) * NN + row) * HH + c8;
    const short* p1 = pacc + ((size_t)(z * 2 + 1) * NN + row) * HH + c8;
    const float* bias = z ? bias1 : bias0;
    short* X = (z ? X1 : X0) + (size_t)row * HH + c8;
    bf16x8 a = *(const bf16x8*)p0, b = *(const bf16x8*)p1;
    bf16x8 o;
    #pragma unroll
    for (int q = 0; q < 8; ++q)
        o[q] = f2b(lrelu(b2f(a[q]) + b2f(b[q]) + bias[c8 + q]));
    *(bf16x8*)X = o;
}

// ---------------------------------------------------------------------------
// s1[i] = H[i,:] . a[0:128] ; s2[i] = H[i,:] . a[128:256]
// ---------------------------------------------------------------------------
__global__ void s12_kernel(
    const float* __restrict__ H0, const float* __restrict__ H1,
    const float* __restrict__ a0, const float* __restrict__ a1,
    float* __restrict__ s1_0, float* __restrict__ s1_1,
    float* __restrict__ s2_0, float* __restrict__ s2_1)
{
    const int z = blockIdx.y;
    const float* H = z ? H1 : H0;
    const float* a = z ? a1 : a0;
    float* s1 = z ? s1_1 : s1_0;
    float* s2 = z ? s2_1 : s2_0;

    const int i = blockIdx.x, t = threadIdx.x;   // 64 threads
    float h0 = H[(size_t)i * FF + t];
    float h1 = H[(size_t)i * FF + 64 + t];
    float v1 = h0 * a[t] + h1 * a[64 + t];
    float v2 = h0 * a[128 + t] + h1 * a[192 + t];
    #pragma unroll
    for (int off = 32; off > 0; off >>= 1) {
        v1 += __shfl_down(v1, off);
        v2 += __shfl_down(v2, off);
    }
    if (t == 0) { s1[i] = v1; s2[i] = v2; }
}

// ---------------------------------------------------------------------------
// Global s2 max per mod (safe softmax shift upper bound; shift-invariant).
// ---------------------------------------------------------------------------
__global__ __launch_bounds__(256) void s2max_kernel(
    const float* __restrict__ s2_0, const float* __restrict__ s2_1,
    float* __restrict__ s2mx)
{
    const int z = blockIdx.x;
    const float* s2v = z ? s2_1 : s2_0;
    __shared__ float red[4];
    float M = -3.0e38f;
    for (int i = threadIdx.x; i < NN; i += 256) M = fmaxf(M, s2v[i]);
    #pragma unroll
    for (int off = 32; off > 0; off >>= 1) M = fmaxf(M, __shfl_xor(M, off));
    if ((threadIdx.x & 63) == 0) red[threadIdx.x >> 6] = M;
    __syncthreads();
    if (threadIdx.x == 0)
        s2mx[z] = fmaxf(fmaxf(red[0], red[1]), fmaxf(red[2], red[3]));
}

// ---------------------------------------------------------------------------
// WAVE-INDEPENDENT GAT (unchanged — passed, fast).
// ---------------------------------------------------------------------------
struct BFr {
    bf16x8 b0, b1, b2, b3, b4, b5, b6, b7;
};

__global__ __launch_bounds__(256) void gat_wave(
    const unsigned char* __restrict__ MK0, const unsigned char* __restrict__ MK1,
    const short* __restrict__ HF0, const short* __restrict__ HF1,
    const float* __restrict__ s1_0, const float* __restrict__ s1_1,
    const float* __restrict__ s2_0, const float* __restrict__ s2_1,
    float* __restrict__ pacc, const float* __restrict__ s2mx,
    float* __restrict__ pl)
{
    const int sp = blockIdx.y, z = blockIdx.z;
    const unsigned char* MK = z ? MK1 : MK0;
    const short* HFp  = z ? HF1 : HF0;
    const float* s1v  = z ? s1_1 : s1_0;
    const float* s2v  = z ? s2_1 : s2_0;
    const int jb = sp * 1024;

    const int tid = threadIdx.x;
    const int l = tid & 63, w = tid >> 6;
    const int fr = l & 15, fq = l >> 4;
    const int i0 = blockIdx.x * 64 + w * 16;      // wave-private 16 rows

    const size_t base = (size_t)(z * 4 + sp) * NN + i0;
    const float s1r = s1v[i0 + fr];
    const float mfix = lrelu(s1r + s2mx[z]);
    float lsum = 0.f;
    f32x4v acc0 = {0.f,0.f,0.f,0.f}, acc1 = {0.f,0.f,0.f,0.f};
    f32x4v acc2 = {0.f,0.f,0.f,0.f}, acc3 = {0.f,0.f,0.f,0.f};
    f32x4v acc4 = {0.f,0.f,0.f,0.f}, acc5 = {0.f,0.f,0.f,0.f};
    f32x4v acc6 = {0.f,0.f,0.f,0.f}, acc7 = {0.f,0.f,0.f,0.f};

    const unsigned char* mrow = MK + (size_t)(i0 + fr) * 512;
    const short* hfl = HFp + fr * 32 + fq * 8;    // lane offset inside tile
    const unsigned shm = fq * 8;                  // mask byte shift

    BFr BA, BB;

    auto loadB = [&](BFr& B, int J) {             // J multiple of 32
        const short* tb = hfl + (size_t)(J >> 5) * 4096;
        B.b0 = *(const bf16x8*)(tb + 0 * 512);
        B.b1 = *(const bf16x8*)(tb + 1 * 512);
        B.b2 = *(const bf16x8*)(tb + 2 * 512);
        B.b3 = *(const bf16x8*)(tb + 3 * 512);
        B.b4 = *(const bf16x8*)(tb + 4 * 512);
        B.b5 = *(const bf16x8*)(tb + 5 * 512);
        B.b6 = *(const bf16x8*)(tb + 6 * 512);
        B.b7 = *(const bf16x8*)(tb + 7 * 512);
    };

    auto subc = [&](BFr& B, int J, unsigned mb) {
        const float* sp2 = s2v + J + fq * 8;
        float4 sA = *(const float4*)(sp2);
        float4 sB = *(const float4*)(sp2 + 4);
        float e0 = (mb & 1u)   ? lrelu(s1r + sA.x) : -1e12f;
        float e1 = (mb & 2u)   ? lrelu(s1r + sA.y) : -1e12f;
        float e2 = (mb & 4u)   ? lrelu(s1r + sA.z) : -1e12f;
        float e3 = (mb & 8u)   ? lrelu(s1r + sA.w) : -1e12f;
        float e4 = (mb & 16u)  ? lrelu(s1r + sB.x) : -1e12f;
        float e5 = (mb & 32u)  ? lrelu(s1r + sB.y) : -1e12f;
        float e6 = (mb & 64u)  ? lrelu(s1r + sB.z) : -1e12f;
        float e7 = (mb & 128u) ? lrelu(s1r + sB.w) : -1e12f;
        float w0 = __expf(e0 - mfix), w1 = __expf(e1 - mfix);
        float w2 = __expf(e2 - mfix), w3 = __expf(e3 - mfix);
        float w4 = __expf(e4 - mfix), w5 = __expf(e5 - mfix);
        float w6 = __expf(e6 - mfix), w7 = __expf(e7 - mfix);
        lsum += ((w0 + w1) + (w2 + w3)) + ((w4 + w5) + (w6 + w7));
        bf16x8 av;
        av[0] = f2b(w0); av[1] = f2b(w1); av[2] = f2b(w2); av[3] = f2b(w3);
        av[4] = f2b(w4); av[5] = f2b(w5); av[6] = f2b(w6); av[7] = f2b(w7);
        acc0 = __builtin_amdgcn_mfma_f32_16x16x32_bf16(av, B.b0, acc0, 0, 0, 0);
        acc1 = __builtin_amdgcn_mfma_f32_16x16x32_bf16(av, B.b1, acc1, 0, 0, 0);
        acc2 = __builtin_amdgcn_mfma_f32_16x16x32_bf16(av, B.b2, acc2, 0, 0, 0);
        acc3 = __builtin_amdgcn_mfma_f32_16x16x32_bf16(av, B.b3, acc3, 0, 0, 0);
        acc4 = __builtin_amdgcn_mfma_f32_16x16x32_bf16(av, B.b4, acc4, 0, 0, 0);
        acc5 = __builtin_amdgcn_mfma_f32_16x16x32_bf16(av, B.b5, acc5, 0, 0, 0);
        acc6 = __builtin_amdgcn_mfma_f32_16x16x32_bf16(av, B.b6, acc6, 0, 0, 0);
        acc7 = __builtin_amdgcn_mfma_f32_16x16x32_bf16(av, B.b7, acc7, 0, 0, 0);
    };

    loadB(BA, jb);
    for (int c = 0; c < 8; ++c) {                 // 8 chunks x 128 j
        const int C = jb + c * 128;
        uint4 mk = *(const uint4*)(mrow + (C >> 3));
        loadB(BB, C + 32);
        subc(BA, C,       (mk.x >> shm) & 255u);
        loadB(BA, C + 64);
        subc(BB, C + 32,  (mk.y >> shm) & 255u);
        loadB(BB, C + 96);
        subc(BA, C + 64,  (mk.z >> shm) & 255u);
        if (c < 7) loadB(BA, C + 128);
        subc(BB, C + 96,  (mk.w >> shm) & 255u);
    }

    // row-fr total over the 4 fq lane-groups
    lsum += __shfl_xor(lsum, 16);
    lsum += __shfl_xor(lsum, 32);

    #pragma unroll
    for (int q = 0; q < 4; ++q) {
        float* Pr = pacc + (base + fq * 4 + q) * FF + fr;
        Pr[0]   = acc0[q];
        Pr[16]  = acc1[q];
        Pr[32]  = acc2[q];
        Pr[48]  = acc3[q];
        Pr[64]  = acc4[q];
        Pr[80]  = acc5[q];
        Pr[96]  = acc6[q];
        Pr[112] = acc7[q];
    }
    if (l < 16) pl[base + fr] = lsum;
}

// ---------------------------------------------------------------------------
// Combine 4 j-splits -> O = lrelu((a0+..+a3)/(l0+..+l3))
// ---------------------------------------------------------------------------
__global__ __launch_bounds__(256) void gat_combine(
    const float* __restrict__ pacc, const float* __restrict__ pl,
    float* __restrict__ O0, float* __restrict__ O1)
{
    const int idx = blockIdx.x * 256 + threadIdx.x;   // 0 .. 2*4096*128-1
    const int z = idx >> 19;
    const int rem = idx & 524287;
    const int row = rem >> 7, f = rem & 127;
    float a = 0.f, lt = 0.f;
    #pragma unroll
    for (int s = 0; s < 4; ++s) {
        const size_t b = (size_t)(z * 4 + s) * NN + row;
        a  += pacc[b * FF + f];
        lt += pl[b];
    }
    float* Op = z ? O1 : O0;
    Op[(size_t)row * FF + f] = lrelu(a / lt);
}

// ---------------------------------------------------------------------------
// PoE + 3 predictors + softmax (unchanged)
// ---------------------------------------------------------------------------
__global__ __launch_bounds__(128) void final_fused(
    const float* __restrict__ O0, const float* __restrict__ O1,
    const float* __restrict__ mask,
    const float* __restrict__ jpW1, const float* __restrict__ jpb1,
    const float* __restrict__ jpW2, const float* __restrict__ jpb2,
    const float* __restrict__ sW1_0, const float* __restrict__ sb1_0,
    const float* __restrict__ sW2_0, const float* __restrict__ sb2_0,
    const float* __restrict__ sW1_1, const float* __restrict__ sb1_1,
    const float* __restrict__ sW2_1, const float* __restrict__ sb2_1,
    float* __restrict__ out)
{
    __shared__ float zbuf[3][64];
    __shared__ float hbuf[3][128];
    __shared__ float lg[16];

    const int i = blockIdx.x, t = threadIdx.x;

    if (t < 64) {
        float mu0 = O0[(size_t)i * FF + t];
        float lv0 = O0[(size_t)i * FF + 64 + t];
        float mu1 = O1[(size_t)i * FF + t];
        float lv1 = O1[(size_t)i * FF + 64 + t];
        float p0 = 1.f / (__expf(lv0) + 1e-8f);
        float p1 = 1.f / (__expf(lv1) + 1e-8f);
        float mk0 = mask[(size_t)i * 2 + 0];
        float mk1 = mask[(size_t)i * 2 + 1];
        float tmp = 1.f + mk0 * p0 + mk1 * p1;
        float jv = 1.f / (tmp + 1e-8f);
        zbuf[0][t] = jv * (mk0 * p0 * mu0 + mk1 * p1 * mu1);
        zbuf[1][t] = mu0;
        zbuf[2][t] = mu1;
    }
    __syncthreads();

    {
        float s0 = jpb1[t], s1 = sb1_0[t], s2 = sb1_1[t];
        for (int k = 0; k < 64; ++k) {
            float z0 = zbuf[0][k], z1 = zbuf[1][k], z2 = zbuf[2][k];
            s0 = fmaf(z0, jpW1[k * PH + t], s0);
            s1 = fmaf(z1, sW1_0[k * PH + t], s1);
            s2 = fmaf(z2, sW1_1[k * PH + t], s2);
        }
        hbuf[0][t] = lrelu(s0);
        hbuf[1][t] = lrelu(s1);
        hbuf[2][t] = lrelu(s2);
    }
    __syncthreads();

    if (t < 15) {
        int p = t / 5, c = t % 5;
        const float* W2 = (p == 0) ? jpW2 : (p == 1 ? sW2_0 : sW2_1);
        const float* b2 = (p == 0) ? jpb2 : (p == 1 ? sb2_0 : sb2_1);
        float s = b2[c];
        for (int k = 0; k < 128; ++k) s = fmaf(hbuf[p][k], W2[k * YY + c], s);
        lg[t] = s;
    }
    __syncthreads();

    if (t < 3) {
        float mx = -3e38f;
        #pragma unroll
        for (int c = 0; c < 5; ++c) mx = fmaxf(mx, lg[t * 5 + c]);
        float ex[5], sum = 0.f;
        #pragma unroll
        for (int c = 0; c < 5; ++c) { ex[c] = __expf(lg[t * 5 + c] - mx); sum += ex[c]; }
        #pragma unroll
        for (int c = 0; c < 5; ++c)
            out[(size_t)i * 15 + t * 5 + c] = ex[c] / sum;
    }
}

// ---------------------------------------------------------------------------
extern "C" void kernel_launch(void* const* d_in, const int* in_sizes, int n_in,
                              void* d_out, int out_size, void* d_ws, size_t ws_size,
                              hipStream_t stream)
{
    const float* x[2]   = {(const float*)d_in[0],  (const float*)d_in[12]};
    const float* adj[2] = {(const float*)d_in[1],  (const float*)d_in[13]};
    const float* g1W[2] = {(const float*)d_in[2],  (const float*)d_in[14]};
    const float* g1b[2] = {(const float*)d_in[3],  (const float*)d_in[15]};
    const float* g2W[2] = {(const float*)d_in[4],  (const float*)d_in[16]};
    const float* g2b[2] = {(const float*)d_in[5],  (const float*)d_in[17]};
    const float* gaW[2] = {(const float*)d_in[6],  (const float*)d_in[18]};
    const float* gaA[2] = {(const float*)d_in[7],  (const float*)d_in[19]};
    const float* sW1[2] = {(const float*)d_in[8],  (const float*)d_in[20]};
    const float* sb1[2] = {(const float*)d_in[9],  (const float*)d_in[21]};
    const float* sW2[2] = {(const float*)d_in[10], (const float*)d_in[22]};
    const float* sb2[2] = {(const float*)d_in[11], (const float*)d_in[23]};
    const float* mask   = (const float*)d_in[24];
    const float* jpW1   = (const float*)d_in[25];
    const float* jpb1   = (const float*)d_in[26];
    const float* jpW2   = (const float*)d_in[27];
    const float* jpb2   = (const float*)d_in[28];
    float* out = (float*)d_out;

    const size_t NH = (size_t)NN * HH;   // 1,048,576
    const size_t NF = (size_t)NN * FF;   //   524,288
    float* p = (float*)d_ws;
    short* STb = (short*)p;  p += NH;             // STf frag-tiled x2 (4MB)
    short* W1T = (short*)p;  p += (2 * 256 * 448) / 2;
    short* W2T = (short*)p;  p += (2 * 256 * 256) / 2;
    short* gWT = (short*)p;  p += (2 * 128 * 256) / 2;
    float* s1b = p;          p += 2 * NN;
    float* s2b = p;          p += 2 * NN;
    unsigned char* MKb = (unsigned char*)p;  p += (2 * (size_t)NN * 512) / 4;  // 4 MB
    short* HFb = (short*)p;  p += NF;             // HF bf16 x2 (2MB)
    float* Ob  = p;          p += 2 * NF;         // O fp32 x2 (4MB)
    float* s2mx = p;         p += 2;
    float* plb = p;          p += 2 * 4 * NN;     // gat per-split l (4 splits)
    // 16MB UNION (liveness-disjoint):
    //   steps 2-5: XB bf16 (4MB) + H fp32 (4MB) + adj bf16 partials (8MB)
    //   step 7   : gat fp32 partials [2mod][4sp][4096][128] (16MB)
    float* UN = p;           p += 4 * NH;
    short* XBb = (short*)UN;                       // 2 mods x NH shorts
    float* Hb  = UN + NH;                          // 2 mods x NF floats
    short* PAb = (short*)(UN + NH + 2 * NF);       // adj partials, 4NH shorts
    float* GPa = UN;                               // gat pacc (whole union)
    // total ~ 31.1 MB

    short* ST[2] = {STb, STb + NH};
    short* XB[2] = {XBb, XBb + NH};
    float* H[2]  = {Hb, Hb + NF};
    short* HF[2] = {HFb, HFb + NF};
    short* W1Tp[2] = {W1T, W1T + 256 * 448};
    short* W2Tp[2] = {W2T, W2T + 256 * 256};
    short* gWTp[2] = {gWT, gWT + 128 * 256};
    float* s1p[2] = {s1b, s1b + NN};
    float* s2p[2] = {s2b, s2b + NN};
    unsigned char* MK[2] = {MKb, MKb + (size_t)NN * 512};
    float* O[2]  = {Ob, Ob + NF};

    // 0. weight preps: W^T bf16 (pad K)
    transpose_f2b_pad<<<dim3(256/32, 448/32, 2), 256, 0, stream>>>(
        g1W[0], g1W[1], W1Tp[0], W1Tp[1], 400, 256, 448);
    transpose_f2b_pad<<<dim3(256/32, 256/32, 2), 256, 0, stream>>>(
        g2W[0], g2W[1], W2Tp[0], W2Tp[1], 256, 256, 256);
    transpose_f2b_pad<<<dim3(128/32, 256/32, 2), 256, 0, stream>>>(
        gaW[0], gaW[1], gWTp[0], gWTp[1], 256, 128, 256);

    // 1. STf = frag-tiled (x @ W1) bf16   (MFMA, A fp32 K=400 pad 448, N=256)
    gemm_mfma_gen<false, false, true, 7><<<dim3(HH/64, NN/64, 2), 256, 0, stream>>>(
        (const void*)x[0], (const void*)x[1], W1Tp[0], W1Tp[1],
        nullptr, nullptr, ST[0], ST[1], DD, 448, HH, 400);
    // 2. split-K adj GEMM 1 (+ sign mask) -> bf16 partials; combine -> X1
    gemm_mfma_adj<true><<<dim3(NN/32, 2, 2), 512, 0, stream>>>(
        adj[0], adj[1], ST[0], ST[1], PAb, MK[0], MK[1]);
    adj_combine<<<dim3(2 * NN * HH / 8 / 256), 256, 0, stream>>>(
        PAb, g1b[0], g1b[1], XB[0], XB[1]);
    // 3. STf = frag-tiled (X1 @ W2) bf16  (MFMA, A bf16 K=256, N=256)
    gemm_mfma_gen<true, false, true, 4><<<dim3(HH/64, NN/64, 2), 256, 0, stream>>>(
        (const void*)XB[0], (const void*)XB[1], W2Tp[0], W2Tp[1],
        nullptr, nullptr, ST[0], ST[1], HH, HH, HH, 256);
    // 4. split-K adj GEMM 2 -> bf16 partials; combine -> X2
    gemm_mfma_adj<false><<<dim3(NN/32, 2, 2), 512, 0, stream>>>(
        adj[0], adj[1], ST[0], ST[1], PAb, nullptr, nullptr);
    adj_combine<<<dim3(2 * NN * HH / 8 / 256), 256, 0, stream>>>(
        PAb, g2b[0], g2b[1], XB[0], XB[1]);
    // 5. H fp32 + HF (frag-tiled bf16, N=128) = X2 @ gaW
    gemm_mfma_gen<true, true, true, 4><<<dim3(FF/64, NN/64, 2), 256, 0, stream>>>(
        (const void*)XB[0], (const void*)XB[1], gWTp[0], gWTp[1],
        H[0], H[1], HF[0], HF[1], HH, HH, FF, 256);
    // 6. s1/s2
    s12_kernel<<<dim3(NN, 2), 64, 0, stream>>>(
        H[0], H[1], gaA[0], gaA[1], s1p[0], s1p[1], s2p[0], s2p[1]);
    // 6b. global s2 max per mod (2 blocks)
    s2max_kernel<<<dim3(2), 256, 0, stream>>>(s2p[0], s2p[1], s2mx);
    // 7. wave-independent GAT, 4-way j-split -> fp32 partials (union region)
    gat_wave<<<dim3(NN/64, 4, 2), 256, 0, stream>>>(
        MK[0], MK[1], HF[0], HF[1], s1p[0], s1p[1], s2p[0], s2p[1],
        GPa, s2mx, plb);
    // 7b. combine -> O fp32
    gat_combine<<<dim3((2 * NN * FF) / 256), 256, 0, stream>>>(
        GPa, plb, O[0], O[1]);
    // 8. PoE + predictors + softmax -> out [4096,15]
    final_fused<<<NN, 128, 0, stream>>>(
        O[0], O[1], mask,
        jpW1, jpb1, jpW2, jpb2,
        sW1[0], sb1[0], sW2[0], sb2[0],
        sW1[1], sb1[1], sW2[1], sb2[1],
        out);
}

// Round 20
// 205.709 us; speedup vs baseline: 1.0031x; 1.0031x over previous
//
#include <hip/hip_runtime.h>
#include <math.h>

// Problem dims (fixed)
#define NN 4096     // nodes
#define DD 400      // input feature dim
#define HH 256      // GCN hidden
#define FF 128      // GAT out dim
#define PH 128      // predictor hidden
#define YY 5        // classes

typedef float f32x4v __attribute__((ext_vector_type(4)));
typedef short bf16x8 __attribute__((ext_vector_type(8)));
typedef short bf16x4 __attribute__((ext_vector_type(4)));

__device__ __forceinline__ float lrelu(float v) { return v >= 0.f ? v : 0.25f * v; }
// fp32 -> bf16 round-to-nearest-even
__device__ __forceinline__ short f2b(float f) {
    unsigned u = __float_as_uint(f);
    unsigned r = (u + 0x7fffu + ((u >> 16) & 1u)) >> 16;
    return (short)r;
}
__device__ __forceinline__ float b2f(short s) {
    return __uint_as_float((unsigned)(unsigned short)s << 16);
}

// Raw LDS-visibility barrier (no vmcnt drain).
__device__ __forceinline__ void bar_stage() {
    asm volatile("s_waitcnt lgkmcnt(0)" ::: "memory");
    __builtin_amdgcn_sched_barrier(0);
    __builtin_amdgcn_s_barrier();
    __builtin_amdgcn_sched_barrier(0);
}
__device__ __forceinline__ void bar_read() {
    __builtin_amdgcn_sched_barrier(0);
    __builtin_amdgcn_s_barrier();
    __builtin_amdgcn_sched_barrier(0);
}

// ---------------------------------------------------------------------------
// Weight prep: in [R,C] fp32 -> out [C,RP] bf16 (transpose, zero-pad rows>=R)
// ---------------------------------------------------------------------------
__global__ __launch_bounds__(256) void transpose_f2b_pad(
    const float* __restrict__ in0, const float* __restrict__ in1,
    short* __restrict__ out0, short* __restrict__ out1, int R, int C, int RP)
{
    const float* in = blockIdx.z ? in1 : in0;
    short* out      = blockIdx.z ? out1 : out0;
    __shared__ float T[32][33];
    const int r0 = blockIdx.y * 32, c0 = blockIdx.x * 32;
    const int t = threadIdx.x, r = t >> 5, c = t & 31;
    #pragma unroll
    for (int p = 0; p < 4; ++p) {
        int rr = r0 + r + p * 8;
        T[r + p * 8][c] = (rr < R) ? in[(size_t)rr * C + c0 + c] : 0.f;
    }
    __syncthreads();
    #pragma unroll
    for (int p = 0; p < 4; ++p)
        out[(size_t)(c0 + r + p * 8) * RP + r0 + c] = f2b(T[c][r + p * 8]);
}

// ---------------------------------------------------------------------------
// Generic bf16 MFMA GEMM (steps 1,3,5). WHF: fragment-tiled output
// CF[m/32][n=N][m&31] (tile = N*32 shorts) — used for STf (N=256) and HF
// (N=128). WC: row-major fp32 C.
// ---------------------------------------------------------------------------
struct PrefMM {
    float4 a0, a1, a2, a3;    // A fp32 path
    bf16x8 ab0, ab1;          // A bf16 path
    bf16x8 b0, b1;            // B
};

template<bool ABF16, bool WC, bool WHF, int KSTEPS>
__global__ __launch_bounds__(256) void gemm_mfma_gen(
    const void* __restrict__ A0, const void* __restrict__ A1,
    const short* __restrict__ BT0, const short* __restrict__ BT1,
    float* __restrict__ C0, float* __restrict__ C1,
    short* __restrict__ CT0, short* __restrict__ CT1,
    int lda, int ldb, int N, int kvalid)
{
    const void* A   = blockIdx.z ? A1 : A0;
    const short* BT = blockIdx.z ? BT1 : BT0;
    float* C        = blockIdx.z ? C1 : C0;
    short* CT       = blockIdx.z ? CT1 : CT0;

    __shared__ short As[64 * 88];
    __shared__ short Bs[64 * 88];

    const int tid = threadIdx.x;
    const int m0 = blockIdx.y * 64, n0 = blockIdx.x * 64;
    const int l = tid & 63, w = tid >> 6;
    const int wr = w >> 1, wc = w & 1;
    const int fr = l & 15, fq = l >> 4;
    const int sr = tid >> 2, sk = (tid & 3) * 16;

    const float* Apf = (const float*)A + (size_t)(m0 + sr) * lda + sk;
    const short* Apb = (const short*)A + (size_t)(m0 + sr) * lda + sk;
    const short* Bp  = BT + (size_t)(n0 + sr) * ldb + sk;

    short* As_w = As + sr * 88 + sk;
    short* Bs_w = Bs + sr * 88 + sk;
    const short* Af = As + (wr * 32 + fr) * 88 + fq * 8;
    const short* Bf = Bs + (wc * 32 + fr) * 88 + fq * 8;

    f32x4v acc00 = {0.f,0.f,0.f,0.f}, acc01 = {0.f,0.f,0.f,0.f};
    f32x4v acc10 = {0.f,0.f,0.f,0.f}, acc11 = {0.f,0.f,0.f,0.f};

    PrefMM P[2];

    auto loadr = [&](PrefMM& Pr, int t) {
        const int kk = t * 64;
        const bool valid = (kk + sk) < kvalid;
        if (ABF16) {
            if (valid) {
                Pr.ab0 = *(const bf16x8*)(Apb + kk);
                Pr.ab1 = *(const bf16x8*)(Apb + kk + 8);
            } else {
                Pr.ab0 = (bf16x8)0; Pr.ab1 = (bf16x8)0;
            }
        } else {
            if (valid) {
                Pr.a0 = *(const float4*)(Apf + kk);
                Pr.a1 = *(const float4*)(Apf + kk + 4);
                Pr.a2 = *(const float4*)(Apf + kk + 8);
                Pr.a3 = *(const float4*)(Apf + kk + 12);
            } else {
                Pr.a0 = Pr.a1 = Pr.a2 = Pr.a3 = make_float4(0.f, 0.f, 0.f, 0.f);
            }
        }
        Pr.b0 = *(const bf16x8*)(Bp + kk);
        Pr.b1 = *(const bf16x8*)(Bp + kk + 8);
    };

    auto stage = [&](PrefMM& Pr) {
        if (ABF16) {
            *(bf16x8*)(As_w)     = Pr.ab0;
            *(bf16x8*)(As_w + 8) = Pr.ab1;
        } else {
            bf16x8 v0, v1;
            v0[0] = f2b(Pr.a0.x); v0[1] = f2b(Pr.a0.y); v0[2] = f2b(Pr.a0.z); v0[3] = f2b(Pr.a0.w);
            v0[4] = f2b(Pr.a1.x); v0[5] = f2b(Pr.a1.y); v0[6] = f2b(Pr.a1.z); v0[7] = f2b(Pr.a1.w);
            v1[0] = f2b(Pr.a2.x); v1[1] = f2b(Pr.a2.y); v1[2] = f2b(Pr.a2.z); v1[3] = f2b(Pr.a2.w);
            v1[4] = f2b(Pr.a3.x); v1[5] = f2b(Pr.a3.y); v1[6] = f2b(Pr.a3.z); v1[7] = f2b(Pr.a3.w);
            *(bf16x8*)(As_w)     = v0;
            *(bf16x8*)(As_w + 8) = v1;
        }
        *(bf16x8*)(Bs_w)     = Pr.b0;
        *(bf16x8*)(Bs_w + 8) = Pr.b1;
    };

    auto mfma16 = [&]() {
        bf16x8 A00 = *(const bf16x8*)(Af);
        bf16x8 A10 = *(const bf16x8*)(Af + 16 * 88);
        bf16x8 A01 = *(const bf16x8*)(Af + 32);
        bf16x8 A11 = *(const bf16x8*)(Af + 16 * 88 + 32);
        bf16x8 B00 = *(const bf16x8*)(Bf);
        bf16x8 B10 = *(const bf16x8*)(Bf + 16 * 88);
        bf16x8 B01 = *(const bf16x8*)(Bf + 32);
        bf16x8 B11 = *(const bf16x8*)(Bf + 16 * 88 + 32);
        acc00 = __builtin_amdgcn_mfma_f32_16x16x32_bf16(A00, B00, acc00, 0, 0, 0);
        acc01 = __builtin_amdgcn_mfma_f32_16x16x32_bf16(A00, B10, acc01, 0, 0, 0);
        acc10 = __builtin_amdgcn_mfma_f32_16x16x32_bf16(A10, B00, acc10, 0, 0, 0);
        acc11 = __builtin_amdgcn_mfma_f32_16x16x32_bf16(A10, B10, acc11, 0, 0, 0);
        acc00 = __builtin_amdgcn_mfma_f32_16x16x32_bf16(A01, B01, acc00, 0, 0, 0);
        acc01 = __builtin_amdgcn_mfma_f32_16x16x32_bf16(A01, B11, acc01, 0, 0, 0);
        acc10 = __builtin_amdgcn_mfma_f32_16x16x32_bf16(A11, B01, acc10, 0, 0, 0);
        acc11 = __builtin_amdgcn_mfma_f32_16x16x32_bf16(A11, B11, acc11, 0, 0, 0);
    };

    loadr(P[0], 0);
    #pragma unroll
    for (int t = 0; t < KSTEPS; ++t) {
        if (t + 1 < KSTEPS) loadr(P[(t + 1) & 1], t + 1);
        stage(P[t & 1]);
        bar_stage();
        mfma16();
        bar_read();
    }

    const int crow = m0 + wr * 32 + fq * 4;
    const int col0 = n0 + wc * 32 + fr;
    if (WHF) {
        // CF[jt = m>>5][n][m&31]; tile = N*32. m = crow+q and crow+16+q.
        const int jt = (m0 >> 5) + wr;
        short* hf = CT + (size_t)jt * (N * 32) + fq * 4;
        bf16x4 u;
        u[0]=f2b(acc00[0]); u[1]=f2b(acc00[1]); u[2]=f2b(acc00[2]); u[3]=f2b(acc00[3]);
        *(bf16x4*)(hf + col0 * 32) = u;
        u[0]=f2b(acc01[0]); u[1]=f2b(acc01[1]); u[2]=f2b(acc01[2]); u[3]=f2b(acc01[3]);
        *(bf16x4*)(hf + (col0 + 16) * 32) = u;
        u[0]=f2b(acc10[0]); u[1]=f2b(acc10[1]); u[2]=f2b(acc10[2]); u[3]=f2b(acc10[3]);
        *(bf16x4*)(hf + col0 * 32 + 16) = u;
        u[0]=f2b(acc11[0]); u[1]=f2b(acc11[1]); u[2]=f2b(acc11[2]); u[3]=f2b(acc11[3]);
        *(bf16x4*)(hf + (col0 + 16) * 32 + 16) = u;
    }
    if (WC) {
        #pragma unroll
        for (int q = 0; q < 4; ++q) {
            C[(size_t)(crow + q) * N + col0]           = acc00[q];
            C[(size_t)(crow + q) * N + col0 + 16]      = acc01[q];
            C[(size_t)(crow + 16 + q) * N + col0]      = acc10[q];
            C[(size_t)(crow + 16 + q) * N + col0 + 16] = acc11[q];
        }
    }
}

// ---------------------------------------------------------------------------
// adj GEMM (steps 2,4): B direct from frag-tiled STf; A via 4.5KB LDS tile.
// Split-K=2, depth-4 A prefetch (round-18 best: 71.5us/dispatch).
// ---------------------------------------------------------------------------
struct PAdj { float4 a0, a1; };
struct PBf  { bf16x8 b00, b01, b10, b11; };

template<bool WMASK>
__global__ __launch_bounds__(512) void gemm_mfma_adj(
    const float* __restrict__ A0p, const float* __restrict__ A1p,
    const short* __restrict__ BF0, const short* __restrict__ BF1,
    short* __restrict__ pacc,
    unsigned char* __restrict__ MK0, unsigned char* __restrict__ MK1)
{
    const int sp = blockIdx.y, z = blockIdx.z;
    const float* A    = z ? A1p : A0p;
    const short* BF   = z ? BF1 : BF0;
    unsigned char* MK = z ? MK1 : MK0;
    const int kbase = sp * 2048;

    __shared__ short As[32 * 72];     // 4.5 KB

    const int tid = threadIdx.x;
    const int m0 = blockIdx.x * 32;
    const int w = tid >> 6, l = tid & 63;
    const int fr = l & 15, fq = l >> 4;

    // A staging (threads 0..255): row ar (0..31), 8 k per thread
    const bool doA = (tid < 256);
    const int ar = (tid & 255) >> 3, ak = (tid & 7) * 8;
    const float* Ap = A + (size_t)(m0 + ar) * 4096 + kbase + ak;
    short* As_w = As + ar * 72 + ak;
    unsigned char* mrow = MK + (size_t)(m0 + ar) * 512 + sp * 256 + (tid & 7);

    // B fragment base: STf[kt][n=256][k&31]; this wave's cols w*32 + fr (+16)
    const short* Bp = BF + (size_t)(sp * 64) * 8192 + (w * 32 + fr) * 32 + fq * 8;

    const short* Af0 = As + fr * 72 + fq * 8;          // rows 0..15
    const short* Af1 = As + (16 + fr) * 72 + fq * 8;   // rows 16..31

    f32x4v acc00 = {0.f,0.f,0.f,0.f}, acc01 = {0.f,0.f,0.f,0.f};
    f32x4v acc10 = {0.f,0.f,0.f,0.f}, acc11 = {0.f,0.f,0.f,0.f};

    PAdj A0r, A1r, A2r, A3r;
    PBf  B0r, B1r;

    auto loadA = [&](PAdj& P, int it) {
        if (doA) {
            P.a0 = *(const float4*)(Ap + it * 64);
            P.a1 = *(const float4*)(Ap + it * 64 + 4);
        }
    };
    auto loadB = [&](PBf& P, int it) {
        const short* tb = Bp + (size_t)(it * 2) * 8192;
        P.b00 = *(const bf16x8*)(tb);
        P.b01 = *(const bf16x8*)(tb + 512);          // cols +16
        P.b10 = *(const bf16x8*)(tb + 8192);         // kt+1
        P.b11 = *(const bf16x8*)(tb + 8192 + 512);
    };
    auto stageA = [&](PAdj& P, int it) {
        if (doA) {
            bf16x8 av;
            av[0] = f2b(P.a0.x); av[1] = f2b(P.a0.y); av[2] = f2b(P.a0.z); av[3] = f2b(P.a0.w);
            av[4] = f2b(P.a1.x); av[5] = f2b(P.a1.y); av[6] = f2b(P.a1.z); av[7] = f2b(P.a1.w);
            *(bf16x8*)As_w = av;
            if (WMASK) {
                unsigned mb = (P.a0.x > 0.f ? 1u : 0u)  | (P.a0.y > 0.f ? 2u : 0u) |
                              (P.a0.z > 0.f ? 4u : 0u)  | (P.a0.w > 0.f ? 8u : 0u) |
                              (P.a1.x > 0.f ? 16u : 0u) | (P.a1.y > 0.f ? 32u : 0u) |
                              (P.a1.z > 0.f ? 64u : 0u) | (P.a1.w > 0.f ? 128u : 0u);
                mrow[it * 8] = (unsigned char)mb;
            }
        }
    };
    auto mfma8 = [&](PBf& B) {
        bf16x8 A00 = *(const bf16x8*)(Af0);          // k 0..31
        bf16x8 A01 = *(const bf16x8*)(Af0 + 32);     // k 32..63
        bf16x8 A10 = *(const bf16x8*)(Af1);
        bf16x8 A11 = *(const bf16x8*)(Af1 + 32);
        acc00 = __builtin_amdgcn_mfma_f32_16x16x32_bf16(A00, B.b00, acc00, 0, 0, 0);
        acc01 = __builtin_amdgcn_mfma_f32_16x16x32_bf16(A00, B.b01, acc01, 0, 0, 0);
        acc10 = __builtin_amdgcn_mfma_f32_16x16x32_bf16(A10, B.b00, acc10, 0, 0, 0);
        acc11 = __builtin_amdgcn_mfma_f32_16x16x32_bf16(A10, B.b01, acc11, 0, 0, 0);
        acc00 = __builtin_amdgcn_mfma_f32_16x16x32_bf16(A01, B.b10, acc00, 0, 0, 0);
        acc01 = __builtin_amdgcn_mfma_f32_16x16x32_bf16(A01, B.b11, acc01, 0, 0, 0);
        acc10 = __builtin_amdgcn_mfma_f32_16x16x32_bf16(A11, B.b10, acc10, 0, 0, 0);
        acc11 = __builtin_amdgcn_mfma_f32_16x16x32_bf16(A11, B.b11, acc11, 0, 0, 0);
    };

    loadA(A0r, 0); loadA(A1r, 1); loadA(A2r, 2); loadA(A3r, 3);
    loadB(B0r, 0);
    for (int it = 0; it < 32; it += 4) {
        stageA(A0r, it);
        if (it + 4 < 32) loadA(A0r, it + 4);
        loadB(B1r, it + 1);
        bar_stage();
        mfma8(B0r);
        bar_read();

        stageA(A1r, it + 1);
        if (it + 5 < 32) loadA(A1r, it + 5);
        loadB(B0r, it + 2);
        bar_stage();
        mfma8(B1r);
        bar_read();

        stageA(A2r, it + 2);
        if (it + 6 < 32) loadA(A2r, it + 6);
        loadB(B1r, it + 3);
        bar_stage();
        mfma8(B0r);
        bar_read();

        stageA(A3r, it + 3);
        if (it + 7 < 32) loadA(A3r, it + 7);
        if (it + 4 < 32) loadB(B0r, it + 4);
        bar_stage();
        mfma8(B1r);
        bar_read();
    }

    const int ccol = w * 32 + fr;
    #pragma unroll
    for (int q = 0; q < 4; ++q) {
        short* P0 = pacc + ((size_t)(z * 2 + sp) * NN + m0 + fq * 4 + q) * HH;
        short* P1 = P0 + 16 * HH;
        P0[ccol]      = f2b(acc00[q]);
        P0[ccol + 16] = f2b(acc01[q]);
        P1[ccol]      = f2b(acc10[q]);
        P1[ccol + 16] = f2b(acc11[q]);
    }
}

// ---------------------------------------------------------------------------
// Combine split-K partials: X = bf16(lrelu(p0 + p1 + bias)). 8 cols/thread.
// ---------------------------------------------------------------------------
__global__ __launch_bounds__(256) void adj_combine(
    const short* __restrict__ pacc,
    const float* __restrict__ bias0, const float* __restrict__ bias1,
    short* __restrict__ X0, short* __restrict__ X1)
{
    const int idx = blockIdx.x * 256 + threadIdx.x;   // 0 .. 2*4096*32-1
    const int z = idx >> 17, rem = idx & 131071;
    const int row = rem >> 5, c8 = (rem & 31) * 8;
    const short* p0 = pacc + ((size_t)(z * 2 + 0) * NN + row) * HH + c8;
    const short* p1 = pacc + ((size_t)(z * 2 + 1) * NN + row) * HH + c8;
    const float* bias = z ? bias1 : bias0;
    short* X = (z ? X1 : X0) + (size_t)row * HH + c8;
    bf16x8 a = *(const bf16x8*)p0, b = *(const bf16x8*)p1;
    bf16x8 o;
    #pragma unroll
    for (int q = 0; q < 8; ++q)
        o[q] = f2b(lrelu(b2f(a[q]) + b2f(b[q]) + bias[c8 + q]));
    *(bf16x8*)X = o;
}

// ---------------------------------------------------------------------------
// s1[i] = H[i,:] . a[0:128] ; s2[i] = H[i,:] . a[128:256]
// ---------------------------------------------------------------------------
__global__ void s12_kernel(
    const float* __restrict__ H0, const float* __restrict__ H1,
    const float* __restrict__ a0, const float* __restrict__ a1,
    float* __restrict__ s1_0, float* __restrict__ s1_1,
    float* __restrict__ s2_0, float* __restrict__ s2_1)
{
    const int z = blockIdx.y;
    const float* H = z ? H1 : H0;
    const float* a = z ? a1 : a0;
    float* s1 = z ? s1_1 : s1_0;
    float* s2 = z ? s2_1 : s2_0;

    const int i = blockIdx.x, t = threadIdx.x;   // 64 threads
    float h0 = H[(size_t)i * FF + t];
    float h1 = H[(size_t)i * FF + 64 + t];
    float v1 = h0 * a[t] + h1 * a[64 + t];
    float v2 = h0 * a[128 + t] + h1 * a[192 + t];
    #pragma unroll
    for (int off = 32; off > 0; off >>= 1) {
        v1 += __shfl_down(v1, off);
        v2 += __shfl_down(v2, off);
    }
    if (t == 0) { s1[i] = v1; s2[i] = v2; }
}

// ---------------------------------------------------------------------------
// Global s2 max per mod (safe softmax shift upper bound; shift-invariant).
// ---------------------------------------------------------------------------
__global__ __launch_bounds__(256) void s2max_kernel(
    const float* __restrict__ s2_0, const float* __restrict__ s2_1,
    float* __restrict__ s2mx)
{
    const int z = blockIdx.x;
    const float* s2v = z ? s2_1 : s2_0;
    __shared__ float red[4];
    float M = -3.0e38f;
    for (int i = threadIdx.x; i < NN; i += 256) M = fmaxf(M, s2v[i]);
    #pragma unroll
    for (int off = 32; off > 0; off >>= 1) M = fmaxf(M, __shfl_xor(M, off));
    if ((threadIdx.x & 63) == 0) red[threadIdx.x >> 6] = M;
    __syncthreads();
    if (threadIdx.x == 0)
        s2mx[z] = fmaxf(fmaxf(red[0], red[1]), fmaxf(red[2], red[3]));
}

// ---------------------------------------------------------------------------
// WAVE-INDEPENDENT GAT (unchanged — passed, fast).
// ---------------------------------------------------------------------------
struct BFr {
    bf16x8 b0, b1, b2, b3, b4, b5, b6, b7;
};

__global__ __launch_bounds__(256) void gat_wave(
    const unsigned char* __restrict__ MK0, const unsigned char* __restrict__ MK1,
    const short* __restrict__ HF0, const short* __restrict__ HF1,
    const float* __restrict__ s1_0, const float* __restrict__ s1_1,
    const float* __restrict__ s2_0, const float* __restrict__ s2_1,
    float* __restrict__ pacc, const float* __restrict__ s2mx,
    float* __restrict__ pl)
{
    const int sp = blockIdx.y, z = blockIdx.z;
    const unsigned char* MK = z ? MK1 : MK0;
    const short* HFp  = z ? HF1 : HF0;
    const float* s1v  = z ? s1_1 : s1_0;
    const float* s2v  = z ? s2_1 : s2_0;
    const int jb = sp * 1024;

    const int tid = threadIdx.x;
    const int l = tid & 63, w = tid >> 6;
    const int fr = l & 15, fq = l >> 4;
    const int i0 = blockIdx.x * 64 + w * 16;      // wave-private 16 rows

    const size_t base = (size_t)(z * 4 + sp) * NN + i0;
    const float s1r = s1v[i0 + fr];
    const float mfix = lrelu(s1r + s2mx[z]);
    float lsum = 0.f;
    f32x4v acc0 = {0.f,0.f,0.f,0.f}, acc1 = {0.f,0.f,0.f,0.f};
    f32x4v acc2 = {0.f,0.f,0.f,0.f}, acc3 = {0.f,0.f,0.f,0.f};
    f32x4v acc4 = {0.f,0.f,0.f,0.f}, acc5 = {0.f,0.f,0.f,0.f};
    f32x4v acc6 = {0.f,0.f,0.f,0.f}, acc7 = {0.f,0.f,0.f,0.f};

    const unsigned char* mrow = MK + (size_t)(i0 + fr) * 512;
    const short* hfl = HFp + fr * 32 + fq * 8;    // lane offset inside tile
    const unsigned shm = fq * 8;                  // mask byte shift

    BFr BA, BB;

    auto loadB = [&](BFr& B, int J) {             // J multiple of 32
        const short* tb = hfl + (size_t)(J >> 5) * 4096;
        B.b0 = *(const bf16x8*)(tb + 0 * 512);
        B.b1 = *(const bf16x8*)(tb + 1 * 512);
        B.b2 = *(const bf16x8*)(tb + 2 * 512);
        B.b3 = *(const bf16x8*)(tb + 3 * 512);
        B.b4 = *(const bf16x8*)(tb + 4 * 512);
        B.b5 = *(const bf16x8*)(tb + 5 * 512);
        B.b6 = *(const bf16x8*)(tb + 6 * 512);
        B.b7 = *(const bf16x8*)(tb + 7 * 512);
    };

    auto subc = [&](BFr& B, int J, unsigned mb) {
        const float* sp2 = s2v + J + fq * 8;
        float4 sA = *(const float4*)(sp2);
        float4 sB = *(const float4*)(sp2 + 4);
        float e0 = (mb & 1u)   ? lrelu(s1r + sA.x) : -1e12f;
        float e1 = (mb & 2u)   ? lrelu(s1r + sA.y) : -1e12f;
        float e2 = (mb & 4u)   ? lrelu(s1r + sA.z) : -1e12f;
        float e3 = (mb & 8u)   ? lrelu(s1r + sA.w) : -1e12f;
        float e4 = (mb & 16u)  ? lrelu(s1r + sB.x) : -1e12f;
        float e5 = (mb & 32u)  ? lrelu(s1r + sB.y) : -1e12f;
        float e6 = (mb & 64u)  ? lrelu(s1r + sB.z) : -1e12f;
        float e7 = (mb & 128u) ? lrelu(s1r + sB.w) : -1e12f;
        float w0 = __expf(e0 - mfix), w1 = __expf(e1 - mfix);
        float w2 = __expf(e2 - mfix), w3 = __expf(e3 - mfix);
        float w4 = __expf(e4 - mfix), w5 = __expf(e5 - mfix);
        float w6 = __expf(e6 - mfix), w7 = __expf(e7 - mfix);
        lsum += ((w0 + w1) + (w2 + w3)) + ((w4 + w5) + (w6 + w7));
        bf16x8 av;
        av[0] = f2b(w0); av[1] = f2b(w1); av[2] = f2b(w2); av[3] = f2b(w3);
        av[4] = f2b(w4); av[5] = f2b(w5); av[6] = f2b(w6); av[7] = f2b(w7);
        acc0 = __builtin_amdgcn_mfma_f32_16x16x32_bf16(av, B.b0, acc0, 0, 0, 0);
        acc1 = __builtin_amdgcn_mfma_f32_16x16x32_bf16(av, B.b1, acc1, 0, 0, 0);
        acc2 = __builtin_amdgcn_mfma_f32_16x16x32_bf16(av, B.b2, acc2, 0, 0, 0);
        acc3 = __builtin_amdgcn_mfma_f32_16x16x32_bf16(av, B.b3, acc3, 0, 0, 0);
        acc4 = __builtin_amdgcn_mfma_f32_16x16x32_bf16(av, B.b4, acc4, 0, 0, 0);
        acc5 = __builtin_amdgcn_mfma_f32_16x16x32_bf16(av, B.b5, acc5, 0, 0, 0);
        acc6 = __builtin_amdgcn_mfma_f32_16x16x32_bf16(av, B.b6, acc6, 0, 0, 0);
        acc7 = __builtin_amdgcn_mfma_f32_16x16x32_bf16(av, B.b7, acc7, 0, 0, 0);
    };

    loadB(BA, jb);
    for (int c = 0; c < 8; ++c) {                 // 8 chunks x 128 j
        const int C = jb + c * 128;
        uint4 mk = *(const uint4*)(mrow + (C >> 3));
        loadB(BB, C + 32);
        subc(BA, C,       (mk.x >> shm) & 255u);
        loadB(BA, C + 64);
        subc(BB, C + 32,  (mk.y >> shm) & 255u);
        loadB(BB, C + 96);
        subc(BA, C + 64,  (mk.z >> shm) & 255u);
        if (c < 7) loadB(BA, C + 128);
        subc(BB, C + 96,  (mk.w >> shm) & 255u);
    }

    // row-fr total over the 4 fq lane-groups
    lsum += __shfl_xor(lsum, 16);
    lsum += __shfl_xor(lsum, 32);

    #pragma unroll
    for (int q = 0; q < 4; ++q) {
        float* Pr = pacc + (base + fq * 4 + q) * FF + fr;
        Pr[0]   = acc0[q];
        Pr[16]  = acc1[q];
        Pr[32]  = acc2[q];
        Pr[48]  = acc3[q];
        Pr[64]  = acc4[q];
        Pr[80]  = acc5[q];
        Pr[96]  = acc6[q];
        Pr[112] = acc7[q];
    }
    if (l < 16) pl[base + fr] = lsum;
}

// ---------------------------------------------------------------------------
// Combine 4 j-splits -> O = lrelu((a0+..+a3)/(l0+..+l3))
// ---------------------------------------------------------------------------
__global__ __launch_bounds__(256) void gat_combine(
    const float* __restrict__ pacc, const float* __restrict__ pl,
    float* __restrict__ O0, float* __restrict__ O1)
{
    const int idx = blockIdx.x * 256 + threadIdx.x;   // 0 .. 2*4096*128-1
    const int z = idx >> 19;
    const int rem = idx & 524287;
    const int row = rem >> 7, f = rem & 127;
    float a = 0.f, lt = 0.f;
    #pragma unroll
    for (int s = 0; s < 4; ++s) {
        const size_t b = (size_t)(z * 4 + s) * NN + row;
        a  += pacc[b * FF + f];
        lt += pl[b];
    }
    float* Op = z ? O1 : O0;
    Op[(size_t)row * FF + f] = lrelu(a / lt);
}

// ---------------------------------------------------------------------------
// PoE + 3 predictors + softmax (unchanged)
// ---------------------------------------------------------------------------
__global__ __launch_bounds__(128) void final_fused(
    const float* __restrict__ O0, const float* __restrict__ O1,
    const float* __restrict__ mask,
    const float* __restrict__ jpW1, const float* __restrict__ jpb1,
    const float* __restrict__ jpW2, const float* __restrict__ jpb2,
    const float* __restrict__ sW1_0, const float* __restrict__ sb1_0,
    const float* __restrict__ sW2_0, const float* __restrict__ sb2_0,
    const float* __restrict__ sW1_1, const float* __restrict__ sb1_1,
    const float* __restrict__ sW2_1, const float* __restrict__ sb2_1,
    float* __restrict__ out)
{
    __shared__ float zbuf[3][64];
    __shared__ float hbuf[3][128];
    __shared__ float lg[16];

    const int i = blockIdx.x, t = threadIdx.x;

    if (t < 64) {
        float mu0 = O0[(size_t)i * FF + t];
        float lv0 = O0[(size_t)i * FF + 64 + t];
        float mu1 = O1[(size_t)i * FF + t];
        float lv1 = O1[(size_t)i * FF + 64 + t];
        float p0 = 1.f / (__expf(lv0) + 1e-8f);
        float p1 = 1.f / (__expf(lv1) + 1e-8f);
        float mk0 = mask[(size_t)i * 2 + 0];
        float mk1 = mask[(size_t)i * 2 + 1];
        float tmp = 1.f + mk0 * p0 + mk1 * p1;
        float jv = 1.f / (tmp + 1e-8f);
        zbuf[0][t] = jv * (mk0 * p0 * mu0 + mk1 * p1 * mu1);
        zbuf[1][t] = mu0;
        zbuf[2][t] = mu1;
    }
    __syncthreads();

    {
        float s0 = jpb1[t], s1 = sb1_0[t], s2 = sb1_1[t];
        for (int k = 0; k < 64; ++k) {
            float z0 = zbuf[0][k], z1 = zbuf[1][k], z2 = zbuf[2][k];
            s0 = fmaf(z0, jpW1[k * PH + t], s0);
            s1 = fmaf(z1, sW1_0[k * PH + t], s1);
            s2 = fmaf(z2, sW1_1[k * PH + t], s2);
        }
        hbuf[0][t] = lrelu(s0);
        hbuf[1][t] = lrelu(s1);
        hbuf[2][t] = lrelu(s2);
    }
    __syncthreads();

    if (t < 15) {
        int p = t / 5, c = t % 5;
        const float* W2 = (p == 0) ? jpW2 : (p == 1 ? sW2_0 : sW2_1);
        const float* b2 = (p == 0) ? jpb2 : (p == 1 ? sb2_0 : sb2_1);
        float s = b2[c];
        for (int k = 0; k < 128; ++k) s = fmaf(hbuf[p][k], W2[k * YY + c], s);
        lg[t] = s;
    }
    __syncthreads();

    if (t < 3) {
        float mx = -3e38f;
        #pragma unroll
        for (int c = 0; c < 5; ++c) mx = fmaxf(mx, lg[t * 5 + c]);
        float ex[5], sum = 0.f;
        #pragma unroll
        for (int c = 0; c < 5; ++c) { ex[c] = __expf(lg[t * 5 + c] - mx); sum += ex[c]; }
        #pragma unroll
        for (int c = 0; c < 5; ++c)
            out[(size_t)i * 15 + t * 5 + c] = ex[c] / sum;
    }
}

// ---------------------------------------------------------------------------
extern "C" void kernel_launch(void* const* d_in, const int* in_sizes, int n_in,
                              void* d_out, int out_size, void* d_ws, size_t ws_size,
                              hipStream_t stream)
{
    const float* x[2]   = {(const float*)d_in[0],  (const float*)d_in[12]};
    const float* adj[2] = {(const float*)d_in[1],  (const float*)d_in[13]};
    const float* g1W[2] = {(const float*)d_in[2],  (const float*)d_in[14]};
    const float* g1b[2] = {(const float*)d_in[3],  (const float*)d_in[15]};
    const float* g2W[2] = {(const float*)d_in[4],  (const float*)d_in[16]};
    const float* g2b[2] = {(const float*)d_in[5],  (const float*)d_in[17]};
    const float* gaW[2] = {(const float*)d_in[6],  (const float*)d_in[18]};
    const float* gaA[2] = {(const float*)d_in[7],  (const float*)d_in[19]};
    const float* sW1[2] = {(const float*)d_in[8],  (const float*)d_in[20]};
    const float* sb1[2] = {(const float*)d_in[9],  (const float*)d_in[21]};
    const float* sW2[2] = {(const float*)d_in[10], (const float*)d_in[22]};
    const float* sb2[2] = {(const float*)d_in[11], (const float*)d_in[23]};
    const float* mask   = (const float*)d_in[24];
    const float* jpW1   = (const float*)d_in[25];
    const float* jpb1   = (const float*)d_in[26];
    const float* jpW2   = (const float*)d_in[27];
    const float* jpb2   = (const float*)d_in[28];
    float* out = (float*)d_out;

    const size_t NH = (size_t)NN * HH;   // 1,048,576
    const size_t NF = (size_t)NN * FF;   //   524,288
    float* p = (float*)d_ws;
    short* STb = (short*)p;  p += NH;             // STf frag-tiled x2 (4MB)
    short* W1T = (short*)p;  p += (2 * 256 * 448) / 2;
    short* W2T = (short*)p;  p += (2 * 256 * 256) / 2;
    short* gWT = (short*)p;  p += (2 * 128 * 256) / 2;
    float* s1b = p;          p += 2 * NN;
    float* s2b = p;          p += 2 * NN;
    unsigned char* MKb = (unsigned char*)p;  p += (2 * (size_t)NN * 512) / 4;  // 4 MB
    short* HFb = (short*)p;  p += NF;             // HF bf16 x2 (2MB)
    float* Ob  = p;          p += 2 * NF;         // O fp32 x2 (4MB)
    float* s2mx = p;         p += 2;
    float* plb = p;          p += 2 * 4 * NN;     // gat per-split l (4 splits)
    // 16MB UNION (liveness-disjoint):
    //   steps 2-5: XB bf16 (4MB) + H fp32 (4MB) + adj bf16 partials (8MB)
    //   step 7   : gat fp32 partials [2mod][4sp][4096][128] (16MB)
    float* UN = p;           p += 4 * NH;
    short* XBb = (short*)UN;                       // 2 mods x NH shorts
    float* Hb  = UN + NH;                          // 2 mods x NF floats
    short* PAb = (short*)(UN + NH + 2 * NF);       // adj partials, 4NH shorts
    float* GPa = UN;                               // gat pacc (whole union)
    // total ~ 31.1 MB

    short* ST[2] = {STb, STb + NH};
    short* XB[2] = {XBb, XBb + NH};
    float* H[2]  = {Hb, Hb + NF};
    short* HF[2] = {HFb, HFb + NF};
    short* W1Tp[2] = {W1T, W1T + 256 * 448};
    short* W2Tp[2] = {W2T, W2T + 256 * 256};
    short* gWTp[2] = {gWT, gWT + 128 * 256};
    float* s1p[2] = {s1b, s1b + NN};
    float* s2p[2] = {s2b, s2b + NN};
    unsigned char* MK[2] = {MKb, MKb + (size_t)NN * 512};
    float* O[2]  = {Ob, Ob + NF};

    // 0. weight preps: W^T bf16 (pad K)
    transpose_f2b_pad<<<dim3(256/32, 448/32, 2), 256, 0, stream>>>(
        g1W[0], g1W[1], W1Tp[0], W1Tp[1], 400, 256, 448);
    transpose_f2b_pad<<<dim3(256/32, 256/32, 2), 256, 0, stream>>>(
        g2W[0], g2W[1], W2Tp[0], W2Tp[1], 256, 256, 256);
    transpose_f2b_pad<<<dim3(128/32, 256/32, 2), 256, 0, stream>>>(
        gaW[0], gaW[1], gWTp[0], gWTp[1], 256, 128, 256);

    // 1. STf = frag-tiled (x @ W1) bf16   (MFMA, A fp32 K=400 pad 448, N=256)
    gemm_mfma_gen<false, false, true, 7><<<dim3(HH/64, NN/64, 2), 256, 0, stream>>>(
        (const void*)x[0], (const void*)x[1], W1Tp[0], W1Tp[1],
        nullptr, nullptr, ST[0], ST[1], DD, 448, HH, 400);
    // 2. split-K adj GEMM 1 (+ sign mask) -> bf16 partials; combine -> X1
    gemm_mfma_adj<true><<<dim3(NN/32, 2, 2), 512, 0, stream>>>(
        adj[0], adj[1], ST[0], ST[1], PAb, MK[0], MK[1]);
    adj_combine<<<dim3(2 * NN * HH / 8 / 256), 256, 0, stream>>>(
        PAb, g1b[0], g1b[1], XB[0], XB[1]);
    // 3. STf = frag-tiled (X1 @ W2) bf16  (MFMA, A bf16 K=256, N=256)
    gemm_mfma_gen<true, false, true, 4><<<dim3(HH/64, NN/64, 2), 256, 0, stream>>>(
        (const void*)XB[0], (const void*)XB[1], W2Tp[0], W2Tp[1],
        nullptr, nullptr, ST[0], ST[1], HH, HH, HH, 256);
    // 4. split-K adj GEMM 2 -> bf16 partials; combine -> X2
    gemm_mfma_adj<false><<<dim3(NN/32, 2, 2), 512, 0, stream>>>(
        adj[0], adj[1], ST[0], ST[1], PAb, nullptr, nullptr);
    adj_combine<<<dim3(2 * NN * HH / 8 / 256), 256, 0, stream>>>(
        PAb, g2b[0], g2b[1], XB[0], XB[1]);
    // 5. H fp32 + HF (frag-tiled bf16, N=128) = X2 @ gaW
    gemm_mfma_gen<true, true, true, 4><<<dim3(FF/64, NN/64, 2), 256, 0, stream>>>(
        (const void*)XB[0], (const void*)XB[1], gWTp[0], gWTp[1],
        H[0], H[1], HF[0], HF[1], HH, HH, FF, 256);
    // 6. s1/s2
    s12_kernel<<<dim3(NN, 2), 64, 0, stream>>>(
        H[0], H[1], gaA[0], gaA[1], s1p[0], s1p[1], s2p[0], s2p[1]);
    // 6b. global s2 max per mod (2 blocks)
    s2max_kernel<<<dim3(2), 256, 0, stream>>>(s2p[0], s2p[1], s2mx);
    // 7. wave-independent GAT, 4-way j-split -> fp32 partials (union region)
    gat_wave<<<dim3(NN/64, 4, 2), 256, 0, stream>>>(
        MK[0], MK[1], HF[0], HF[1], s1p[0], s1p[1], s2p[0], s2p[1],
        GPa, s2mx, plb);
    // 7b. combine -> O fp32
    gat_combine<<<dim3((2 * NN * FF) / 256), 256, 0, stream>>>(
        GPa, plb, O[0], O[1]);
    // 8. PoE + predictors + softmax -> out [4096,15]
    final_fused<<<NN, 128, 0, stream>>>(
        O[0], O[1], mask,
        jpW1, jpb1, jpW2, jpb2,
        sW1[0], sb1[0], sW2[0], sb2[0],
        sW1[1], sb1[1], sW2[1], sb2[1],
        out);
}